// Round 1
// 431.091 us; speedup vs baseline: 1.1271x; 1.1271x over previous
//
#include <hip/hip_runtime.h>
#include <math.h>

// ---------------- problem constants ----------------
#define NBATCH 16
#define NPTS   1024
#define NANG   12
#define NROTS  60
#define EPSV   1e-5f

// ---------------- workspace layout (float offsets) ----------------
// lifetime-aliased; peak extent = 8455168 floats = 33.8 MB (ws is >=384 MiB per fill counters)
#define WB0_OFF   0          // 64*96 bf16 = 3072 floats
#define WB1_OFF   3072       // 128*160 bf16 = 10240 floats (ends 13312)
#define PART0_OFF 13312      // 16*64*64*12  = 786432
#define PART1_OFF 799744     // 16*64*128*12 = 1572864 (ends 2372608)
#define XF_OFF    13312      // 16*512*60 = 491520 (aliases dead PART after feat_mfma)
#define XM_OFF    504832     // 16*512 = 8192
#define OACT_OFF  513024     // 16*512 = 8192 (ends 521216)
#define XCAT_OFF  2372608    // 16*192*12 = 36864
#define XLIN_OFF  2409472    // 16*256*12 = 49152 (ends 2458624)
#define XG_OFF    2458624    // 960*6144 bf16 = 2949120 floats (ends 5407744)
#define BRP_OFF   2458624    // 16*16*128*60 = 1966080 (aliases XG; XG dead by then)
#define HACT_OFF  4424704    // 16*128*60 = 122880
#define AACT_OFF  4547584    // 16*128*60 = 122880 (ends 4670464)
#define FRAW_OFF  5407744    // 3*512*960 = 1474560 (ends 6882304)
#define FEATW_OFF 6882304    // 512*6144 bf16 = 1572864 floats (ends 8455168) - NO aliasing,
                             // so weight prep can run in the first launch

// ---------------- output layout (float offsets) ----------------
#define OUT_XOUT 0       // (16,256)   = 4096
#define OUT_ATTN 4096    // (16,60)    = 960
#define OUT_PRED 5056    // (16,60,3,3)= 8640
#define OUT_REST 13696   // (16,60,3)  = 2880

typedef short  bf16x8 __attribute__((ext_vector_type(8)));
typedef float  f32x4  __attribute__((ext_vector_type(4)));

// fp32 -> bf16 RNE
__device__ __forceinline__ unsigned short f2bf_rne(float x){
  unsigned int u = __float_as_uint(x);
  u += 0x7FFFu + ((u >> 16) & 1u);
  return (unsigned short)(u >> 16);
}
__device__ __forceinline__ float bf2f(unsigned short h){
  return __uint_as_float(((unsigned int)h) << 16);
}

// pack 8 fp32 -> bf16x8 by truncation (one v_perm_b32 per pair)
__device__ __forceinline__ bf16x8 pack8(const float* f){
  union { unsigned int u[4]; bf16x8 v; } r;
  #pragma unroll
  for (int i = 0; i < 4; i++)
    r.u[i] = __builtin_amdgcn_perm(__float_as_uint(f[2*i+1]),
                                   __float_as_uint(f[2*i]), 0x07060302u);
  return r.v;
}

// async global->LDS 16B (lds base must be wave-uniform; HW adds lane*16)
__device__ __forceinline__ void stage16(const unsigned short* g, unsigned short* l){
  __builtin_amdgcn_global_load_lds((const __attribute__((address_space(1))) void*)g,
                                   (__attribute__((address_space(3))) void*)l, 16, 0, 0);
}

// ---------------- block-wide mean/var helper ----------------
template<int NT>
__device__ __forceinline__ void block_stats(float v, float& m, float& var, float* sbuf){
  constexpr int NW = NT / 64;
  float s = v, s2 = v * v;
  #pragma unroll
  for (int off = 32; off; off >>= 1){
    s  += __shfl_xor(s,  off, 64);
    s2 += __shfl_xor(s2, off, 64);
  }
  const int w = threadIdx.x >> 6;
  if ((threadIdx.x & 63) == 0){ sbuf[w] = s; sbuf[NW + w] = s2; }
  __syncthreads();
  float ts = 0.f, ts2 = 0.f;
  #pragma unroll
  for (int i = 0; i < NW; i++){ ts += sbuf[i]; ts2 += sbuf[NW + i]; }
  m = ts / (float)NT;
  var = ts2 / (float)NT - m * m;
}

// ---------------- prep: all weight conversions in ONE launch ----------------
// blocks [0,24): wb0 (64x96), [24,104): wb1 (128x160), [104,6248): featw hi/lo
template<int C>
__device__ __forceinline__ void prep_wb_body(int idx, const float* __restrict__ W,
                                             unsigned short* __restrict__ Wb){
  constexpr int KPAD = C + 32;
  if (idx >= C * KPAD) return;
  const int o = idx / KPAD, k = idx % KPAD;
  float v = 0.f;
  if (k < C)          v = W[(size_t)o * (C + 3) + 3 + k];
  else if (k < C + 3) v = W[(size_t)o * (C + 3) + (k - C)];
  Wb[idx] = f2bf_rne(v);
}

__global__ __launch_bounds__(256) void prep_all(
    const float* __restrict__ W0, const float* __restrict__ W1,
    const float* __restrict__ FW,
    unsigned short* __restrict__ wb0, unsigned short* __restrict__ wb1,
    unsigned short* __restrict__ fw2){
  const int blk = blockIdx.x;
  if (blk < 24){
    prep_wb_body<64>(blk * 256 + threadIdx.x, W0, wb0);
  } else if (blk < 104){
    prep_wb_body<128>((blk - 24) * 256 + threadIdx.x, W1, wb1);
  } else {
    const int idx = (blk - 104) * 256 + threadIdx.x;   // < 512*3072 exactly
    const int o = idx / 3072, k = idx % 3072;
    const float x = FW[idx];
    const unsigned short hi = f2bf_rne(x);
    const unsigned short lo = f2bf_rne(x - bf2f(hi));
    fw2[(size_t)o * 6144 + k] = hi;
    fw2[(size_t)o * 6144 + 3072 + k] = lo;
  }
}

// ---------------- pointnet GEMM via bf16 MFMA, LDS-staged B, + max over 16 points ----------
// Both pointnets in ONE launch: grid (nchunk=64, b=16, which=2).
// Per block: all C outputs x 192 n (16 points x 12 angles). B tile (32 k x 192 n fp32)
// double-buffered in LDS. LDS row slot sigma(r) = (r&7)*4 + (r>>3), stride 196.
// part layout: [b][nchunk][o][a] -> contiguous 768B stores per m-tile.
#define SROW 196
template<int C>
__device__ __forceinline__ void pn_body(
    const float* __restrict__ xyz, const float* __restrict__ feats,
    const unsigned short* __restrict__ Wb, float* __restrict__ part,
    float* Bs /* 2*32*SROW floats in LDS */){
  constexpr int KPAD = C + 32;
  constexpr int NFK  = C / 32;      // staged feats K-steps
  constexpr int MT   = C / 16;      // m-tiles
  const int nchunk = blockIdx.x, b = blockIdx.y;
  const int tid  = threadIdx.x;
  const int lane = tid & 63, wave = tid >> 6;
  const int g = lane >> 4, l16 = lane & 15;
  const int colbase = wave * 48;
  const int nbase   = nchunk * 192;

  int nn[3], pp[3];
  #pragma unroll
  for (int t = 0; t < 3; t++){
    nn[t] = colbase + t * 16 + l16;          // local n in [0,192)
    pp[t] = (nbase + nn[t]) / 12;            // global point index
  }

  f32x4 acc[MT][3];
  #pragma unroll
  for (int m = 0; m < MT; m++)
    #pragma unroll
    for (int t = 0; t < 3; t++)
      acc[m][t] = (f32x4){0.f, 0.f, 0.f, 0.f};

  const float* fB = feats + (size_t)b * C * (NPTS * NANG) + nbase;

  // staging geometry: 32 rows x 48 float4 chunks = 1536; 6 per thread
  int srow[6], scol[6], sslot[6];
  #pragma unroll
  for (int jj = 0; jj < 6; jj++){
    const int idx = tid + 256 * jj;
    srow[jj]  = idx / 48;
    scol[jj]  = (idx % 48) * 4;
    sslot[jj] = (srow[jj] & 7) * 4 + (srow[jj] >> 3);
  }

  // prologue: stage ks=0 into buf 0
  {
    float4 v[6];
    #pragma unroll
    for (int jj = 0; jj < 6; jj++)
      v[jj] = *(const float4*)(fB + (size_t)srow[jj] * (NPTS * NANG) + scol[jj]);
    #pragma unroll
    for (int jj = 0; jj < 6; jj++)
      *(float4*)(&Bs[sslot[jj] * SROW + scol[jj]]) = v[jj];
  }
  __syncthreads();

  #pragma unroll
  for (int ks = 0; ks < NFK; ks++){
    float* Bc = Bs + (ks & 1) * (32 * SROW);
    float* Bn = Bs + ((ks & 1) ^ 1) * (32 * SROW);
    float4 v[6];
    if (ks + 1 < NFK){
      const int kb = (ks + 1) * 32;
      #pragma unroll
      for (int jj = 0; jj < 6; jj++)
        v[jj] = *(const float4*)(fB + (size_t)(kb + srow[jj]) * (NPTS * NANG) + scol[jj]);
    }
    // compute on current buf (k = ks*32 .. +31)
    const int kb = ks * 32;
    bf16x8 Bf[3];
    #pragma unroll
    for (int t = 0; t < 3; t++){
      float f[8];
      #pragma unroll
      for (int j = 0; j < 8; j++)
        f[j] = Bc[(j * 4 + g) * SROW + nn[t]];   // slot(g*8+j) = j*4+g
      Bf[t] = pack8(f);
    }
    #pragma unroll
    for (int m = 0; m < MT; m++){
      const bf16x8 Af = *(const bf16x8*)(Wb + (size_t)(m * 16 + l16) * KPAD + kb + g * 8);
      #pragma unroll
      for (int t = 0; t < 3; t++)
        acc[m][t] = __builtin_amdgcn_mfma_f32_16x16x32_bf16(Af, Bf[t], acc[m][t], 0, 0, 0);
    }
    if (ks + 1 < NFK){
      #pragma unroll
      for (int jj = 0; jj < 6; jj++)
        *(float4*)(&Bn[sslot[jj] * SROW + scol[jj]]) = v[jj];
    }
    __syncthreads();
  }

  { // xyz K-step (k = C..C+2 non-zero), register B
    const int kb = C;
    bf16x8 Bf[3];
    #pragma unroll
    for (int t = 0; t < 3; t++){
      float f[8];
      #pragma unroll
      for (int j = 0; j < 8; j++) f[j] = 0.f;
      if (g == 0){
        #pragma unroll
        for (int j = 0; j < 3; j++)
          f[j] = xyz[(size_t)(b * 3 + j) * NPTS + pp[t]];
      }
      Bf[t] = pack8(f);
    }
    #pragma unroll
    for (int m = 0; m < MT; m++){
      const bf16x8 Af = *(const bf16x8*)(Wb + (size_t)(m * 16 + l16) * KPAD + kb + g * 8);
      #pragma unroll
      for (int t = 0; t < 3; t++)
        acc[m][t] = __builtin_amdgcn_mfma_f32_16x16x32_bf16(Af, Bf[t], acc[m][t], 0, 0, 0);
    }
  }

  // reduce: per m-tile, stage 16 o x 192 n in LDS (alias buf 0), max over 16 points
  float* yb = Bs;   // 16*196 = 3136 floats <= 6272
  #pragma unroll
  for (int m = 0; m < MT; m++){
    __syncthreads();
    #pragma unroll
    for (int t = 0; t < 3; t++)
      #pragma unroll
      for (int r = 0; r < 4; r++)
        yb[(g * 4 + r) * SROW + nn[t]] = acc[m][t][r];
    __syncthreads();
    if (tid < 192){
      const int o_l = tid / 12, a = tid % 12;
      float mx = -3.4e38f;
      #pragma unroll
      for (int pl = 0; pl < 16; pl++)
        mx = fmaxf(mx, yb[o_l * SROW + pl * 12 + a]);
      // part[b][nchunk][m*16+o_l][a]  (contiguous: base + m*192 + tid)
      part[((size_t)(b * 64 + nchunk) * C + m * 16 + o_l) * 12 + a] = mx;
    }
  }
}

__global__ __launch_bounds__(256) void pn_both(
    const float* __restrict__ xyz0, const float* __restrict__ feats0,
    const unsigned short* __restrict__ wb0, float* __restrict__ part0,
    const float* __restrict__ xyz1, const float* __restrict__ feats1,
    const unsigned short* __restrict__ wb1, float* __restrict__ part1){
  __shared__ float Bs[2 * 32 * SROW];   // 50.2 KB, shared by both paths
  if (blockIdx.z == 0) pn_body<64> (xyz0, feats0, wb0, part0, Bs);
  else                 pn_body<128>(xyz1, feats1, wb1, part1, Bs);
}

// ---------------- reduce chunks + bias + BN + relu -> xcat (16,192,12) ----------------
// part layout: [b][k=64][o][a]
__global__ void pn_reduce_bn(const float* __restrict__ part0, const float* __restrict__ part1,
    const float* __restrict__ b0, const float* __restrict__ g0, const float* __restrict__ bb0,
    const float* __restrict__ b1, const float* __restrict__ g1, const float* __restrict__ bb1,
    float* __restrict__ xcat){
  const int ch = blockIdx.x, t = threadIdx.x;
  const int b = t / 12, a = t % 12;
  const float* part; const float *bias, *g, *bb; int o, Cl;
  if (ch < 64){ part = part0; bias = b0; g = g0; bb = bb0; o = ch;      Cl = 64;  }
  else        { part = part1; bias = b1; g = g1; bb = bb1; o = ch - 64; Cl = 128; }
  const float* pp = part + ((size_t)(b * 64) * Cl + o) * 12 + a;
  const size_t kstride = (size_t)Cl * 12;
  float v = pp[0];
  for (int k = 1; k < 64; k++) v = fmaxf(v, pp[(size_t)k * kstride]);
  v += bias[o];
  __shared__ float sbuf[8];
  float m, var;
  block_stats<192>(v, m, var, sbuf);
  float xn = (v - m) * rsqrtf(var + EPSV) * g[o] + bb[o];
  xcat[((size_t)b * 192 + ch) * 12 + a] = fmaxf(xn, 0.f);
}

// ---------------- lin layer + BN (no relu) -> xlin (16,256,12) ----------------
__global__ void lin_bn(const float* __restrict__ xcat, const float* __restrict__ W,
    const float* __restrict__ bias, const float* __restrict__ g, const float* __restrict__ bb,
    float* __restrict__ xlin){
  const int o = blockIdx.x, t = threadIdx.x;
  const int b = t / 12, a = t % 12;
  const float* xr = xcat + (size_t)b * 2304 + a;
  const float* wr = W + (size_t)o * 192;
  float v = bias[o];
  for (int c = 0; c < 192; c++) v = fmaf(wr[c], xr[(size_t)c * 12], v);
  __shared__ float sbuf[8];
  float m, var;
  block_stats<192>(v, m, var, sbuf);
  xlin[((size_t)b * 256 + o) * 12 + a] = (v - m) * rsqrtf(var + EPSV) * g[o] + bb[o];
}

// ---------------- prep: gathered activations Xg [n=960][hi(3072) | lo(3072)] bf16 ----------------
// n = b*60 + r. Xg[n][c*12+a] = xlin[b][c][trace[a][r]]
__global__ void prep_xg(const float* __restrict__ xlin, const int* __restrict__ trace,
                        unsigned short* __restrict__ Xg){
  const int n = blockIdx.x;           // 0..959
  const int b = n / 60, r = n % 60;
  unsigned short* row = Xg + (size_t)n * 6144;
  __shared__ int ta[12];
  if (threadIdx.x < 12) ta[threadIdx.x] = trace[threadIdx.x * 60 + r];
  __syncthreads();
  for (int i = threadIdx.x; i < 3072; i += 256){
    const int c = i / 12, a = i % 12;
    const float x = xlin[((size_t)b * 256 + c) * 12 + ta[a]];
    const unsigned short hi = f2bf_rne(x);
    const unsigned short lo = f2bf_rne(x - bf2f(hi));
    row[i] = hi;
    row[3072 + i] = lo;
  }
}

// ---------------- feat GEMM: LDS-staged MFMA (m97 pattern), XOR-swizzled chunks ----------------
// C[512,960] = W x Xg^T, 3 hi/lo segments (K=3072 each).
// grid (nblk=15, mblk=8, seg=3); block 256 = 4 waves, wave = 32x32 (2x2 MFMA tiles).
__global__ __launch_bounds__(256) void feat_mfma(
    const unsigned short* __restrict__ Wb2, const unsigned short* __restrict__ Xg,
    float* __restrict__ fraw){
  const int nblk = blockIdx.x, mblk = blockIdx.y, seg = blockIdx.z;
  const int tid = threadIdx.x;
  const int lane = tid & 63, wave = tid >> 6;
  const int g = lane >> 4, l16 = lane & 15;
  const int kA = (seg == 1) ? 3072 : 0;
  const int kB = (seg == 2) ? 3072 : 0;
  const int sw = l16 & 7;
  const int wm = wave >> 1, wn = wave & 1;

  __shared__ unsigned short As[2][64 * 64];
  __shared__ unsigned short Bs[2][64 * 64];

  int rowj[2], colj[2], ldsoff[2];
  #pragma unroll
  for (int j = 0; j < 2; j++){
    const int idx = j * 256 + wave * 64 + lane;
    rowj[j]   = idx >> 3;
    colj[j]   = ((idx & 7) ^ (rowj[j] & 7)) * 8;
    ldsoff[j] = (j * 256 + wave * 64) * 8;
  }
  const unsigned short* Agb = Wb2 + (size_t)mblk * 64 * 6144 + kA;
  const unsigned short* Bgb = Xg  + (size_t)nblk * 64 * 6144 + kB;

  f32x4 acc[2][2];
  #pragma unroll
  for (int i = 0; i < 2; i++)
    #pragma unroll
    for (int j = 0; j < 2; j++)
      acc[i][j] = (f32x4){0.f, 0.f, 0.f, 0.f};

  #pragma unroll
  for (int j = 0; j < 2; j++){
    stage16(Agb + (size_t)rowj[j] * 6144 + colj[j], &As[0][ldsoff[j]]);
    stage16(Bgb + (size_t)rowj[j] * 6144 + colj[j], &Bs[0][ldsoff[j]]);
  }
  __syncthreads();

  for (int kc = 0; kc < 3072; kc += 64){
    const int buf = (kc >> 6) & 1;
    if (kc + 64 < 3072){
      const int kn = kc + 64;
      #pragma unroll
      for (int j = 0; j < 2; j++){
        stage16(Agb + (size_t)rowj[j] * 6144 + kn + colj[j], &As[buf ^ 1][ldsoff[j]]);
        stage16(Bgb + (size_t)rowj[j] * 6144 + kn + colj[j], &Bs[buf ^ 1][ldsoff[j]]);
      }
    }
    #pragma unroll
    for (int kc2 = 0; kc2 < 64; kc2 += 32){
      const int c0 = kc2 >> 3;
      bf16x8 af[2], bfr[2];
      #pragma unroll
      for (int i = 0; i < 2; i++)
        af[i]  = *(const bf16x8*)&As[buf][(wm * 32 + i * 16 + l16) * 64 + ((c0 + g) ^ sw) * 8];
      #pragma unroll
      for (int i = 0; i < 2; i++)
        bfr[i] = *(const bf16x8*)&Bs[buf][(wn * 32 + i * 16 + l16) * 64 + ((c0 + g) ^ sw) * 8];
      #pragma unroll
      for (int i = 0; i < 2; i++)
        #pragma unroll
        for (int j = 0; j < 2; j++)
          acc[i][j] = __builtin_amdgcn_mfma_f32_16x16x32_bf16(af[i], bfr[j], acc[i][j], 0, 0, 0);
    }
    __syncthreads();
  }

  float* base = fraw + (size_t)seg * (512 * 960);
  #pragma unroll
  for (int i = 0; i < 2; i++)
    #pragma unroll
    for (int j = 0; j < 2; j++){
      const int n = nblk * 64 + wn * 32 + j * 16 + l16;
      #pragma unroll
      for (int q = 0; q < 4; q++){
        const int m = mblk * 64 + wm * 32 + i * 16 + g * 4 + q;
        base[(size_t)m * 960 + n] = acc[i][j][q];
      }
    }
}

// ---------------- feat: sum 3 segs + bias + BN + relu + per-b max over r ----------------
__global__ void feat_bn(const float* __restrict__ fraw, const float* __restrict__ bias,
    const float* __restrict__ g, const float* __restrict__ bb,
    float* __restrict__ xf, float* __restrict__ xm){
  const int o = blockIdx.x, t = threadIdx.x;
  const int b = t / 60, r = t % 60;
  const size_t SS = (size_t)512 * 960;
  const size_t in = (size_t)o * 960 + t;
  float v = fraw[in] + fraw[SS + in] + fraw[2 * SS + in] + bias[o];
  __shared__ float sbuf[32];
  float m, var;
  block_stats<960>(v, m, var, sbuf);
  const float xn = fmaxf((v - m) * rsqrtf(var + EPSV) * g[o] + bb[o], 0.f);
  xf[((size_t)b * 512 + o) * 60 + r] = xn;
  __shared__ float red[960];
  red[t] = xn;
  __syncthreads();
  if (r == 0){
    float mx = red[t];
    for (int k = 1; k < 60; k++) mx = fmaxf(mx, red[t + k]);
    xm[(size_t)b * 512 + o] = mx;
  }
}

// ---------------- branch GEMMs fused (reg_W1 & att_W1), K split 8; + out_head1 ----------------
// z < 16: branch GEMM slabs (br=z>>3, ks=z&7).  z == 16: out_head1 (independent work that
// only needs xm -> merged here so it overlaps the branch GEMM instead of a separate launch).
__global__ __launch_bounds__(256) void brgemm_oh1(const float* __restrict__ xf,
    const float* __restrict__ Wr, const float* __restrict__ Wa,
    float* __restrict__ brp,
    const float* __restrict__ xm, const float* __restrict__ oW1,
    const float* __restrict__ ob1, const float* __restrict__ og,
    const float* __restrict__ obb, float* __restrict__ o_act){
  const int z = blockIdx.z;
  if (z == 16){
    // out_head1: 32 useful blocks x 256 threads; t&15=b, t>>4=j, oc = q*16+j
    const int q = blockIdx.y * 4 + blockIdx.x;
    if (q >= 32) return;
    const int t = threadIdx.x;
    const int b = t & 15, j = t >> 4;
    const int oc = q * 16 + j;
    float acc = ob1[oc];
    const float* wr = oW1 + (size_t)oc * 512;
    const float* xr = xm + (size_t)b * 512;
    for (int c = 0; c < 512; c++) acc = fmaf(wr[c], xr[c], acc);
    float s = acc, s2 = acc * acc;
    #pragma unroll
    for (int off = 8; off; off >>= 1){
      s  += __shfl_xor(s,  off, 16);
      s2 += __shfl_xor(s2, off, 16);
    }
    const float m = s * (1.f / 16.f);
    const float var = s2 * (1.f / 16.f) - m * m;
    o_act[(size_t)b * 512 + oc] = fmaxf((acc - m) * rsqrtf(var + EPSV) * og[oc] + obb[oc], 0.f);
    return;
  }
  const int og_ = blockIdx.x, b = blockIdx.y;
  const int br = z >> 3, ks = z & 7;
  const float* W = br ? Wa : Wr;
  const int lane = threadIdx.x & 63, wave = threadIdx.x >> 6;
  const int obase = og_ * 32 + wave * 8;
  const int rr = lane < 60 ? lane : 0;
  const float* xb = xf + ((size_t)b * 512 + ks * 64) * 60 + rr;
  const float* wr = W + (size_t)obase * 512 + ks * 64;

  float acc[8];
  #pragma unroll
  for (int i = 0; i < 8; i++) acc[i] = 0.f;

  float cur[4], nxt[4];
  #pragma unroll
  for (int j = 0; j < 4; j++) cur[j] = xb[(size_t)j * 60];

  for (int c0 = 0; c0 < 64; c0 += 4){
    #pragma unroll
    for (int j = 0; j < 4; j++){
      int cc = c0 + 4 + j; if (cc > 63) cc = 63;
      nxt[j] = xb[(size_t)cc * 60];
    }
    #pragma unroll
    for (int j = 0; j < 4; j++)
      #pragma unroll
      for (int i = 0; i < 8; i++)
        acc[i] = fmaf(wr[(size_t)i * 512 + c0 + j], cur[j], acc[i]);
    #pragma unroll
    for (int j = 0; j < 4; j++) cur[j] = nxt[j];
  }

  if (lane < 60){
    #pragma unroll
    for (int i = 0; i < 8; i++)
      brp[(((size_t)z * NBATCH + b) * 128 + obase + i) * 60 + lane] = acc[i];
  }
}

// ---------------- branch: sum 8 K-slabs + bias + BN + relu ----------------
__global__ void br_bn(const float* __restrict__ brp,
    const float* __restrict__ biasR, const float* __restrict__ gR, const float* __restrict__ bbR,
    const float* __restrict__ biasA, const float* __restrict__ gA, const float* __restrict__ bbA,
    float* __restrict__ hact, float* __restrict__ aact){
  const int o = blockIdx.x, br = blockIdx.y, t = threadIdx.x;
  const int b = t / 60, r = t % 60;
  const float* bias = br ? biasA : biasR;
  const float* g    = br ? gA    : gR;
  const float* bb   = br ? bbA   : bbR;
  float v = bias[o];
  #pragma unroll
  for (int ks = 0; ks < 8; ks++)
    v += brp[((((size_t)br * 8 + ks) * NBATCH + b) * 128 + o) * 60 + r];
  __shared__ float sbuf[32];
  float m, var;
  block_stats<960>(v, m, var, sbuf);
  float* outp = br ? aact : hact;
  outp[((size_t)b * 128 + o) * 60 + r] =
      fmaxf((v - m) * rsqrtf(var + EPSV) * g[o] + bb[o], 0.f);
}

// ---------------- heads: reg2_geom (y=0), att2_softmax (y=1), out_head2 (y=2) in ONE launch ----
__global__ void heads(
    const float* __restrict__ h, const float* __restrict__ rW2,
    const float* __restrict__ rb2, const float* __restrict__ anchors,
    const float* __restrict__ a, const float* __restrict__ aW2, const float* __restrict__ ab2,
    const float* __restrict__ o_act, const float* __restrict__ oW2,
    const float* __restrict__ ob2, float* __restrict__ out){
  const int b = blockIdx.x, sel = blockIdx.y, t = threadIdx.x;
  if (sel == 0){
    // ---- reg head + geometry (c-outer: 128 h loads instead of 896) ----
    if (t >= 64) return;
    const int r = t < 60 ? t : 59;
    float res[7];
    #pragma unroll
    for (int j = 0; j < 7; j++) res[j] = rb2[j];
    for (int c = 0; c < 128; c++){
      const float hv = h[((size_t)b * 128 + c) * 60 + r];
      #pragma unroll
      for (int j = 0; j < 7; j++) res[j] = fmaf(rW2[j * 128 + c], hv, res[j]);
    }
    if (t >= 60) return;
    const float n = sqrtf(res[0]*res[0] + res[1]*res[1] + res[2]*res[2]);
    const float invn = 1.f / n;
    const float Nv = (1.f / (1.f + expf(-res[3])) - 0.5f) * 3.14159265358979323846f / 5.f;
    const float v0 = res[0]*invn*Nv, v1 = res[1]*invn*Nv, v2 = res[2]*invn*Nv;
    const float th = sqrtf(v0*v0 + v1*v1 + v2*v2);
    const float invt = th < 1e-8f ? 1.f : 1.f / th;
    const float k0 = v0*invt, k1 = v1*invt, k2 = v2*invt;
    const float s = sinf(th), cc = 1.f - cosf(th);
    const float K[9] = {0.f, -k2, k1,  k2, 0.f, -k0,  -k1, k0, 0.f};
    float K2[9];
    #pragma unroll
    for (int ii = 0; ii < 3; ii++)
      #pragma unroll
      for (int jj = 0; jj < 3; jj++)
        K2[ii*3+jj] = K[ii*3+0]*K[0*3+jj] + K[ii*3+1]*K[1*3+jj] + K[ii*3+2]*K[2*3+jj];
    float R[9];
    #pragma unroll
    for (int ii = 0; ii < 3; ii++)
      #pragma unroll
      for (int jj = 0; jj < 3; jj++)
        R[ii*3+jj] = (ii == jj ? 1.f : 0.f) + s * K[ii*3+jj] + cc * K2[ii*3+jj];
    const float* A = anchors + (size_t)t * 9;
    #pragma unroll
    for (int ii = 0; ii < 3; ii++)
      #pragma unroll
      for (int kk = 0; kk < 3; kk++){
        const float pv = A[ii*3+0]*R[0*3+kk] + A[ii*3+1]*R[1*3+kk] + A[ii*3+2]*R[2*3+kk];
        out[OUT_PRED + ((size_t)b * 60 + t) * 9 + ii * 3 + kk] = pv;
      }
    #pragma unroll
    for (int k = 0; k < 3; k++)
      out[OUT_REST + ((size_t)b * 60 + t) * 3 + k] = res[4 + k];
  } else if (sel == 1){
    // ---- att head + softmax ----
    if (t >= 64) return;
    const int r = t < 60 ? t : 59;
    float acc = ab2[0];
    for (int c = 0; c < 128; c++)
      acc = fmaf(aW2[c], a[((size_t)b * 128 + c) * 60 + r], acc);
    const float l = t < 60 ? acc : -INFINITY;
    float mx = l;
    #pragma unroll
    for (int off = 32; off; off >>= 1) mx = fmaxf(mx, __shfl_xor(mx, off, 64));
    const float e = t < 60 ? expf(l - mx) : 0.f;
    float ssum = e;
    #pragma unroll
    for (int off = 32; off; off >>= 1) ssum += __shfl_xor(ssum, off, 64);
    if (t < 60) out[OUT_ATTN + (size_t)b * 60 + t] = e / ssum;
  } else {
    // ---- out head 2 ----
    const float* wr = oW2 + (size_t)t * 512;
    const float* xr = o_act + (size_t)b * 512;
    float acc = ob2[t];
    for (int c = 0; c < 512; c++) acc = fmaf(wr[c], xr[c], acc);
    out[OUT_XOUT + (size_t)b * 256 + t] = acc;
  }
}

// ---------------- launch ----------------
extern "C" void kernel_launch(void* const* d_in, const int* in_sizes, int n_in,
                              void* d_out, int out_size, void* d_ws, size_t ws_size,
                              hipStream_t stream){
  const float* xyz0    = (const float*)d_in[0];
  const float* feats0  = (const float*)d_in[1];
  const float* xyz1    = (const float*)d_in[2];
  const float* feats1  = (const float*)d_in[3];
  const int*   trace   = (const int*)  d_in[4];
  const float* anchors = (const float*)d_in[5];
  const float* pn0_W  = (const float*)d_in[6];
  const float* pn0_b  = (const float*)d_in[7];
  const float* pn0_g  = (const float*)d_in[8];
  const float* pn0_bb = (const float*)d_in[9];
  const float* pn1_W  = (const float*)d_in[10];
  const float* pn1_b  = (const float*)d_in[11];
  const float* pn1_g  = (const float*)d_in[12];
  const float* pn1_bb = (const float*)d_in[13];
  const float* lin_W  = (const float*)d_in[14];
  const float* lin_b  = (const float*)d_in[15];
  const float* lin_g  = (const float*)d_in[16];
  const float* lin_bb = (const float*)d_in[17];
  const float* feat_W  = (const float*)d_in[18];
  const float* feat_b  = (const float*)d_in[19];
  const float* feat_g  = (const float*)d_in[20];
  const float* feat_bb = (const float*)d_in[21];
  const float* att_W1 = (const float*)d_in[22];
  const float* att_b1 = (const float*)d_in[23];
  const float* att_g  = (const float*)d_in[24];
  const float* att_bb = (const float*)d_in[25];
  const float* att_W2 = (const float*)d_in[26];
  const float* att_b2 = (const float*)d_in[27];
  const float* reg_W1 = (const float*)d_in[28];
  const float* reg_b1 = (const float*)d_in[29];
  const float* reg_g  = (const float*)d_in[30];
  const float* reg_bb = (const float*)d_in[31];
  const float* reg_W2 = (const float*)d_in[32];
  const float* reg_b2 = (const float*)d_in[33];
  const float* out_W1 = (const float*)d_in[34];
  const float* out_b1 = (const float*)d_in[35];
  const float* out_g  = (const float*)d_in[36];
  const float* out_bb = (const float*)d_in[37];
  const float* out_W2 = (const float*)d_in[38];
  const float* out_b2 = (const float*)d_in[39];

  float* ws  = (float*)d_ws;
  float* out = (float*)d_out;
  unsigned short* wb0 = (unsigned short*)(ws + WB0_OFF);
  unsigned short* wb1 = (unsigned short*)(ws + WB1_OFF);
  unsigned short* fw  = (unsigned short*)(ws + FEATW_OFF);
  unsigned short* xg  = (unsigned short*)(ws + XG_OFF);

  // 1. all weight prep in one launch (featw no longer aliases PART -> safe to run first)
  prep_all<<<6248, 256, 0, stream>>>(pn0_W, pn1_W, feat_W, wb0, wb1, fw);

  // 2. both pointnets in one launch (2048 blocks; removes inter-kernel bubble + tail)
  pn_both<<<dim3(64, 16, 2), 256, 0, stream>>>(xyz0, feats0, wb0, ws + PART0_OFF,
                                               xyz1, feats1, wb1, ws + PART1_OFF);

  // 3. reduce + BN + relu -> concat
  pn_reduce_bn<<<192, 192, 0, stream>>>(ws + PART0_OFF, ws + PART1_OFF,
      pn0_b, pn0_g, pn0_bb, pn1_b, pn1_g, pn1_bb, ws + XCAT_OFF);

  // 4. lin + BN
  lin_bn<<<256, 192, 0, stream>>>(ws + XCAT_OFF, lin_W, lin_b, lin_g, lin_bb, ws + XLIN_OFF);

  // 5. gathered activations hi/lo (N=960, no padding)
  prep_xg<<<960, 256, 0, stream>>>(ws + XLIN_OFF, trace, xg);

  // 6. feat GEMM via LDS-staged MFMA (3 segments)
  feat_mfma<<<dim3(15, 8, 3), 256, 0, stream>>>(fw, xg, ws + FRAW_OFF);

  // 7. sum segs + BN + relu + per-b max
  feat_bn<<<512, 960, 0, stream>>>(ws + FRAW_OFF, feat_b, feat_g, feat_bb,
                                   ws + XF_OFF, ws + XM_OFF);

  // 8. branch GEMMs (K split 8) + out_head1 merged as z=16
  brgemm_oh1<<<dim3(4, 16, 17), 256, 0, stream>>>(ws + XF_OFF, reg_W1, att_W1, ws + BRP_OFF,
      ws + XM_OFF, out_W1, out_b1, out_g, out_bb, ws + OACT_OFF);

  // 9. branch BN
  br_bn<<<dim3(128, 2), 960, 0, stream>>>(ws + BRP_OFF,
      reg_b1, reg_g, reg_bb, att_b1, att_g, att_bb,
      ws + HACT_OFF, ws + AACT_OFF);

  // 10. all remaining heads in one launch (reg geometry / att softmax / out_head2)
  heads<<<dim3(16, 3), 256, 0, stream>>>(ws + HACT_OFF, reg_W2, reg_b2, anchors,
      ws + AACT_OFF, att_W2, att_b2, ws + OACT_OFF, out_W2, out_b2, out);
}